// Round 13
// baseline (39.695 us; speedup 1.0000x reference)
//
#include <hip/hip_runtime.h>
#include <math.h>

// Problem constants
constexpr int Bn = 512;
constexpr int Tn = 512;
constexpr int Dn = 128;
constexpr int Hn = 128;

// Sum across the 16-lane row group via DPP row rotations (pure VALU, no LDS).
__device__ __forceinline__ float rowsum16(float x) {
    int v;
    v = __float_as_int(x);
    x += __int_as_float(__builtin_amdgcn_update_dpp(0, v, 0x121, 0xF, 0xF, true)); // row_ror:1
    v = __float_as_int(x);
    x += __int_as_float(__builtin_amdgcn_update_dpp(0, v, 0x122, 0xF, 0xF, true)); // row_ror:2
    v = __float_as_int(x);
    x += __int_as_float(__builtin_amdgcn_update_dpp(0, v, 0x124, 0xF, 0xF, true)); // row_ror:4
    v = __float_as_int(x);
    x += __int_as_float(__builtin_amdgcn_update_dpp(0, v, 0x128, 0xF, 0xF, true)); // row_ror:8
    return x;
}

// ---------------- K1: u[b] = Wx * (Wt^T * last_visit[b]) ----------------
__global__ __launch_bounds__(128)
void compute_u_kernel(const float* __restrict__ input,   // [B,T,D]
                      const int*   __restrict__ mask,    // [B,T]
                      const float* __restrict__ Wt,      // [D,H]
                      const float* __restrict__ Wx,      // [D,H]
                      float* __restrict__ ws_u)          // [B,D]
{
    const int b   = blockIdx.x;
    const int tid = threadIdx.x;            // 0..127
    const float* __restrict__ inb = input + (size_t)b * Tn * Dn;

    __shared__ float lvs[Dn];
    __shared__ float qs[Hn];
    __shared__ int   ired[2];

    const int4 m4 = ((const int4*)(mask + (size_t)b * Tn))[tid];
    int ms = m4.x + m4.y + m4.z + m4.w;
    #pragma unroll
    for (int off = 32; off > 0; off >>= 1) ms += __shfl_down(ms, off, 64);
    if ((tid & 63) == 0) ired[tid >> 6] = ms;
    __syncthreads();
    const int last_idx = ired[0] + ired[1] - 1;

    lvs[tid] = inb[(size_t)last_idx * Dn + tid];
    __syncthreads();

    float q = 0.f;
    #pragma unroll 16
    for (int d = 0; d < Dn; ++d) q = fmaf(lvs[d], Wt[d * Hn + tid], q);
    qs[tid] = q;
    __syncthreads();

    float u = 0.f;
    const float* wxr = Wx + tid * Hn;
    #pragma unroll 16
    for (int h = 0; h < Hn; ++h) u = fmaf(wxr[h], qs[h], u);
    ws_u[b * Dn + tid] = u;
}

// ---------------- K2: half-batch stream via async global->LDS DMA ----------------
constexpr int NT2    = 512;          // threads per block
constexpr int NW2    = NT2 / 64;     // 8 waves
constexpr int HR     = Tn / 2;       // 256 rows per block
constexpr int RPW    = HR / NW2;     // 32 rows per wave
constexpr int CHROWS = 4;            // rows per chunk (1 chunk = 2 DMA instrs = 2KB)
constexpr int NCH    = RPW / CHROWS; // 8 chunks per wave
constexpr int CB     = 3;            // circular slots per wave
constexpr int CHB    = CHROWS * Dn * 4;  // 2048 bytes per chunk

__global__ __launch_bounds__(NT2, 4)
void attn_stream_dma(const float* __restrict__ input,   // [B,T,D]
                     const int*   __restrict__ mask,    // [B,T]
                     const float* __restrict__ ws_u,    // [B,D]
                     const float* __restrict__ rate,    // [1]
                     float* __restrict__ vpart,         // [2B, D]
                     float* __restrict__ lpart,         // [2B]
                     float* __restrict__ out_a)         // [B,T] (unnormalized p)
{
    const int j     = blockIdx.x;
    const int b     = j >> 1;
    const int half  = j & 1;
    const int tid   = threadIdx.x;
    const int lane  = tid & 63;
    const int w     = tid >> 6;        // wave id 0..7
    const int seg   = lane & 15;       // 16 lanes per row: floats seg*8..seg*8+7
    const int rslot = lane >> 4;       // row-in-chunk 0..3
    const int rbase = half * HR;
    const float* __restrict__ inb = input + (size_t)b * Tn * Dn;

    __shared__ float stream[NW2 * CB * CHROWS * Dn];  // 48 KB wave-private circular buffers
    __shared__ float vp[32 * 132];                    // 16.9 KB v partials
    __shared__ float ps_l[HR];                        // 1 KB unnormalized p
    __shared__ int   msk[HR];                         // 1 KB
    __shared__ float redl[NW2];

    // stage mask + u (everything drains at the following barrier; DMA issued after)
    if (tid < HR) msk[tid] = mask[(size_t)b * Tn + rbase + tid];
    const float4 u4a = ((const float4*)(ws_u + b * Dn))[seg * 2];
    const float4 u4b = ((const float4*)(ws_u + b * Dn))[seg * 2 + 1];
    const float srate = 1.f / (1.f + __expf(-rate[0]));
    __syncthreads();

    // DMA issue: chunk c (4 rows = 2KB) -> wave-private slot c%CB, linear dest
    const char* gwave = (const char*)inb + (size_t)(rbase + w * RPW) * (Dn * 4) + lane * 16;
    char*       lwave = (char*)stream + w * (CB * CHB);
    auto issue = [&](int c) {
        const char* g = gwave + c * CHB;
        char*       l = lwave + (c % CB) * CHB;
        __builtin_amdgcn_global_load_lds((const __attribute__((address_space(1))) void*)g,
                                         (__attribute__((address_space(3))) void*)l, 16, 0, 0);
        __builtin_amdgcn_global_load_lds((const __attribute__((address_space(1))) void*)(g + 1024),
                                         (__attribute__((address_space(3))) void*)(l + 1024), 16, 0, 0);
    };

    issue(0); issue(1); issue(2);   // 6 DMA instrs in flight

    // e = relu(sig/den) in [0, ~1.45] (den >= sigmoid(0.8)*log(2.72) ~= 0.69),
    // so exp(e) <= 4.3: softmax needs no max subtraction.
    float4 v0 = make_float4(0.f, 0.f, 0.f, 0.f);
    float4 v1 = make_float4(0.f, 0.f, 0.f, 0.f);
    float  lsum = 0.f;

    #pragma unroll
    for (int c = 0; c < NCH; ++c) {
        // wait for chunk c only; keep chunks c+1, c+2 in flight (counted vmcnt, never early-0)
        if (c < NCH - 2)      asm volatile("s_waitcnt vmcnt(4)" ::: "memory");
        else if (c == NCH - 2) asm volatile("s_waitcnt vmcnt(2)" ::: "memory");
        else                   asm volatile("s_waitcnt vmcnt(0)" ::: "memory");
        __builtin_amdgcn_sched_barrier(0);

        const float4* sf4 = (const float4*)(lwave + (c % CB) * CHB);
        const float4 x0 = sf4[rslot * 32 + seg * 2];
        const float4 x1 = sf4[rslot * 32 + seg * 2 + 1];

        const int rloc = w * RPW + c * CHROWS + rslot;    // local row in block
        const int row  = rbase + rloc;                    // global t
        float dot = x0.x * u4a.x + x0.y * u4a.y + x0.z * u4a.z + x0.w * u4a.w;
        dot = fmaf(x1.x, u4b.x, dot);
        dot = fmaf(x1.y, u4b.y, dot);
        dot = fmaf(x1.z, u4b.z, dot);
        dot = fmaf(x1.w, u4b.w, dot);
        dot = rowsum16(dot);
        const float sig = 1.f / (1.f + __expf(-dot));
        const float den = srate * (__logf(2.72f + (1.f - sig)) * (float)(Tn - row));
        const float e   = fmaxf(sig / den, 0.f);
        const float p   = msk[rloc] ? __expf(e) : 0.f;
        v0.x = fmaf(p, x0.x, v0.x);
        v0.y = fmaf(p, x0.y, v0.y);
        v0.z = fmaf(p, x0.z, v0.z);
        v0.w = fmaf(p, x0.w, v0.w);
        v1.x = fmaf(p, x1.x, v1.x);
        v1.y = fmaf(p, x1.y, v1.y);
        v1.z = fmaf(p, x1.z, v1.z);
        v1.w = fmaf(p, x1.w, v1.w);
        if (seg == 0) { ps_l[rloc] = p; lsum += p; }

        if (c + CB < NCH) {
            // our ds_reads of slot c%CB have retired (results consumed above);
            // ensure retirement before DMA reuses the slot
            asm volatile("s_waitcnt lgkmcnt(0)" ::: "memory");
            issue(c + CB);
        }
    }

    // stash v partials (group = w*4 + rslot, 32 groups; 16B-aligned: *132 + seg*8)
    {
        float* vr = vp + (w * 4 + rslot) * 132 + seg * 8;
        ((float4*)vr)[0] = v0;
        ((float4*)vr)[1] = v1;
    }
    // block-reduce l (nonzero only on seg==0 lanes)
    float ls = lsum;
    #pragma unroll
    for (int off = 32; off > 0; off >>= 1) ls += __shfl_down(ls, off, 64);
    if (lane == 0) redl[w] = ls;
    __syncthreads();   // vp + ps_l + redl visible

    if (tid < Dn) {
        float s = 0.f;
        #pragma unroll
        for (int r = 0; r < 32; ++r) s += vp[r * 132 + tid];
        vpart[(size_t)j * Dn + tid] = s;
    }
    if (tid == 0) {
        float l = 0.f;
        #pragma unroll
        for (int wv = 0; wv < NW2; ++wv) l += redl[wv];
        lpart[j] = l;
    }
    if (tid < HR) out_a[(size_t)b * Tn + rbase + tid] = ps_l[tid];
}

// ---------------- K3: finish (normalize a, combine v halves) ----------------
__global__ __launch_bounds__(512)
void attn_finish(const float* __restrict__ vpart,   // [2B, D]
                 const float* __restrict__ lpart,   // [2B]
                 float* __restrict__ out_v,         // [B,D]
                 float* __restrict__ out_a)         // [B,T]
{
    const int b   = blockIdx.x;
    const int tid = threadIdx.x;
    const float invl = 1.f / (lpart[2 * b] + lpart[2 * b + 1]);
    out_a[(size_t)b * Tn + tid] *= invl;
    if (tid < Dn)
        out_v[(size_t)b * Dn + tid] =
            (vpart[(size_t)(2 * b) * Dn + tid] + vpart[(size_t)(2 * b + 1) * Dn + tid]) * invl;
}

extern "C" void kernel_launch(void* const* d_in, const int* in_sizes, int n_in,
                              void* d_out, int out_size, void* d_ws, size_t ws_size,
                              hipStream_t stream) {
    const float* input = (const float*)d_in[0];   // [B,T,D]
    const int*   mask  = (const int*)d_in[1];     // [B,T]
    const float* Wt    = (const float*)d_in[2];   // [D,H]
    const float* Wx    = (const float*)d_in[3];   // [D,H]
    const float* rate  = (const float*)d_in[4];   // [1]

    float* out   = (float*)d_out;
    float* out_v = out;                 // [B,D]  (return order: v, a)
    float* out_a = out + Bn * Dn;       // [B,T]

    float* ws_u  = (float*)d_ws;                  // [B,D]
    float* vpart = ws_u + (size_t)Bn * Dn;        // [2B,D]
    float* lpart = vpart + (size_t)2 * Bn * Dn;   // [2B]

    compute_u_kernel<<<Bn, 128, 0, stream>>>(input, mask, Wt, Wx, ws_u);
    attn_stream_dma<<<2 * Bn, NT2, 0, stream>>>(input, mask, ws_u, rate, vpart, lpart, out_a);
    attn_finish<<<Bn, 512, 0, stream>>>(vpart, lpart, out_v, out_a);
}

// Round 15
// 33.304 us; speedup vs baseline: 1.1919x; 1.1919x over previous
//
#include <hip/hip_runtime.h>
#include <math.h>

// Problem constants
constexpr int Bn = 512;
constexpr int Tn = 512;
constexpr int Dn = 128;
constexpr int Hn = 128;
constexpr int NT = 512;       // threads per block (one block per batch)
constexpr int NW = NT / 64;   // 8 waves

typedef float f4 __attribute__((ext_vector_type(4)));   // native vector type: nontemporal-compatible

// Sum across the 16-lane row group via DPP row rotations (pure VALU, no LDS).
__device__ __forceinline__ float rowsum16(float x) {
    int v;
    v = __float_as_int(x);
    x += __int_as_float(__builtin_amdgcn_update_dpp(0, v, 0x121, 0xF, 0xF, true)); // row_ror:1
    v = __float_as_int(x);
    x += __int_as_float(__builtin_amdgcn_update_dpp(0, v, 0x122, 0xF, 0xF, true)); // row_ror:2
    v = __float_as_int(x);
    x += __int_as_float(__builtin_amdgcn_update_dpp(0, v, 0x124, 0xF, 0xF, true)); // row_ror:4
    v = __float_as_int(x);
    x += __int_as_float(__builtin_amdgcn_update_dpp(0, v, 0x128, 0xF, 0xF, true)); // row_ror:8
    return x;
}

__global__ __launch_bounds__(NT, 4)   // VGPR<=128 -> 2 blocks/CU (16 waves/CU)
void single_attn_fused_nt(const float* __restrict__ input,   // [B,T,D]
                          const int*   __restrict__ mask,    // [B,T]
                          const float* __restrict__ Wt,      // [D,H]
                          const float* __restrict__ Wx,      // [D,H]
                          const float* __restrict__ rate,    // [1]
                          float* __restrict__ out_v,         // [B,D]
                          float* __restrict__ out_a)         // [B,T]
{
    const int b    = blockIdx.x;
    const int tid  = threadIdx.x;
    const int lane = tid & 63;
    const int wid  = tid >> 6;
    const int seg  = tid & 15;     // 16 lanes per row; floats seg*8..seg*8+7
    const int rg   = tid >> 4;     // row group 0..31
    const float* __restrict__ inb = input + (size_t)b * Tn * Dn;
    const f4* __restrict__ in4 = (const f4*)inb;

    __shared__ float ps[Tn];          // 2 KB unnormalized weights
    __shared__ int   msk[Tn];         // 2 KB
    __shared__ float lv[Dn];
    __shared__ float qs[Hn];
    __shared__ float us[Dn];
    __shared__ float redl[NW];
    __shared__ int   ired[NW];
    __shared__ float vp[32 * 132];    // 16.9 KB v partials

    // ---- prologue: last_idx, lv, q = lv@Wt, u = Wx@q ----
    const int mv = mask[(size_t)b * Tn + tid];
    msk[tid] = mv;
    {
        int ms = mv;
        #pragma unroll
        for (int off = 32; off > 0; off >>= 1) ms += __shfl_down(ms, off, 64);
        if (lane == 0) ired[wid] = ms;
    }
    __syncthreads();
    int last_idx;
    {
        int s = 0;
        #pragma unroll
        for (int w = 0; w < NW; ++w) s += ired[w];
        last_idx = s - 1;
    }
    if (tid < Dn) lv[tid] = inb[(size_t)last_idx * Dn + tid];
    __syncthreads();
    if (tid < Hn) {
        float a0 = 0.f, a1 = 0.f;
        #pragma unroll 16
        for (int d0 = 0; d0 < Dn; d0 += 2) {
            a0 = fmaf(lv[d0],     Wt[d0 * Hn + tid],       a0);
            a1 = fmaf(lv[d0 + 1], Wt[(d0 + 1) * Hn + tid], a1);
        }
        qs[tid] = a0 + a1;
    }
    __syncthreads();
    if (tid < Dn) {
        float a0 = 0.f, a1 = 0.f;
        const float* wxr = Wx + tid * Hn;
        #pragma unroll 16
        for (int h = 0; h < Hn; h += 2) {
            a0 = fmaf(wxr[h],     qs[h],     a0);
            a1 = fmaf(wxr[h + 1], qs[h + 1], a1);
        }
        us[tid] = a0 + a1;
    }
    __syncthreads();

    const float srate = 1.f / (1.f + __expf(-rate[0]));
    const f4 u4a = ((const f4*)us)[seg * 2];
    const f4 u4b = ((const f4*)us)[seg * 2 + 1];

    // ---- fused streaming pass: dot -> p -> weighted accumulate, input read ONCE ----
    // Non-temporal loads: stream bypasses L1 allocation (data is used exactly once).
    // e = relu(sig/den) in [0, ~1.45] (den >= sigmoid(0.8)*log(2.72) ~= 0.69),
    // so exp(e) <= 4.3: softmax needs no max subtraction.
    f4 v0 = (f4)(0.f);
    f4 v1 = (f4)(0.f);
    float lsum = 0.f;

    #pragma unroll 8
    for (int it = 0; it < 16; ++it) {
        const int row = it * 32 + rg;              // == t
        const f4 x0 = __builtin_nontemporal_load(&in4[row * 32 + seg * 2]);
        const f4 x1 = __builtin_nontemporal_load(&in4[row * 32 + seg * 2 + 1]);
        float dot = x0.x * u4a.x + x0.y * u4a.y + x0.z * u4a.z + x0.w * u4a.w;
        dot = fmaf(x1.x, u4b.x, dot);
        dot = fmaf(x1.y, u4b.y, dot);
        dot = fmaf(x1.z, u4b.z, dot);
        dot = fmaf(x1.w, u4b.w, dot);
        dot = rowsum16(dot);                       // DPP reduce: no DS ops
        const float sig = 1.f / (1.f + __expf(-dot));
        const float den = srate * (__logf(2.72f + (1.f - sig)) * (float)(Tn - row));
        const float e   = fmaxf(sig / den, 0.f);
        const float p   = msk[row] ? __expf(e) : 0.f;
        v0 += p * x0;
        v1 += p * x1;
        if (seg == 0) { ps[row] = p; lsum += p; }
    }

    // stash v partials (16B-aligned: rg*132 + seg*8)
    {
        float* vr = vp + rg * 132 + seg * 8;
        ((f4*)vr)[0] = v0;
        ((f4*)vr)[1] = v1;
    }
    // block-reduce l (nonzero only on seg==0 lanes)
    float ls = lsum;
    #pragma unroll
    for (int off = 32; off > 0; off >>= 1) ls += __shfl_down(ls, off, 64);
    if (lane == 0) redl[wid] = ls;
    __syncthreads();   // vp + ps + redl visible

    float l = 0.f;
    #pragma unroll
    for (int w = 0; w < NW; ++w) l += redl[w];
    const float inv_l = 1.f / l;

    out_a[(size_t)b * Tn + tid] = ps[tid] * inv_l;

    if (tid < Dn) {
        float s = 0.f;
        #pragma unroll
        for (int r = 0; r < 32; ++r) s += vp[r * 132 + tid];
        out_v[(size_t)b * Dn + tid] = s * inv_l;
    }
}

extern "C" void kernel_launch(void* const* d_in, const int* in_sizes, int n_in,
                              void* d_out, int out_size, void* d_ws, size_t ws_size,
                              hipStream_t stream) {
    const float* input = (const float*)d_in[0];   // [B,T,D]
    const int*   mask  = (const int*)d_in[1];     // [B,T]
    const float* Wt    = (const float*)d_in[2];   // [D,H]
    const float* Wx    = (const float*)d_in[3];   // [D,H]
    const float* rate  = (const float*)d_in[4];   // [1]

    float* out   = (float*)d_out;
    float* out_v = out;                 // [B,D]  (return order: v, a)
    float* out_a = out + Bn * Dn;       // [B,T]

    single_attn_fused_nt<<<Bn, NT, 0, stream>>>(input, mask, Wt, Wx, rate, out_v, out_a);
}